// Round 1
// baseline (61.644 us; speedup 1.0000x reference)
//
#include <hip/hip_runtime.h>

#define NWIN 121
#define NQ 10
#define NGATES 23

// Gate schedule (static: depth=3, wires [0..9] -> [0,2,4,6,8] -> [0,4,8]).
// type 0 = fused conv block (u3⊗u3 · XX·YY·ZZ · u3⊗u3), type 1 = CRot.
static constexpr int GT [NGATES] = {0,0,0,0,0,0,0,0,0, 1,1,1,1,1, 0,0,0,0, 1,1, 0,0, 1};
static constexpr int GL [NGATES] = {0,0,0,0,0,0,0,0,0, 0,0,0,0,0, 1,1,1,1, 1,1, 2,2, 2};
static constexpr int GP [NGATES] = {0,2,4,6,8,1,3,5,7, 0,1,2,3,4, 0,2,1,3, 0,1, 0,1, 0};
static constexpr int GQ1[NGATES] = {0,2,4,6,8,1,3,5,7, 1,3,5,7,9, 0,4,2,6, 2,6, 0,4, 4};
static constexpr int GQ2[NGATES] = {1,3,5,7,9,2,4,6,8, 0,2,4,6,8, 2,6,4,8, 0,4, 4,8, 0};

struct cpx { float x, y; };
__device__ __forceinline__ cpx cmul(cpx a, cpx b){ return {a.x*b.x - a.y*b.y, a.x*b.y + a.y*b.x}; }
__device__ __forceinline__ cpx cadd(cpx a, cpx b){ return {a.x+b.x, a.y+b.y}; }
__device__ __forceinline__ cpx cscale(float s, cpx a){ return {s*a.x, s*a.y}; }
__device__ __forceinline__ cpx cexp_i(float t){ return {cosf(t), sinf(t)}; }
__device__ __forceinline__ cpx mulnegi(cpx z){ return {z.y, -z.x}; }   // -i*z

__device__ __forceinline__ void u3m(cpx A[2][2], float th, float ph, float de){
    float ct = cosf(0.5f*th), st = sinf(0.5f*th);
    cpx ed  = cexp_i(de);
    cpx ep  = cexp_i(ph);
    cpx epd = cexp_i(ph + de);
    A[0][0] = {ct, 0.f};
    A[0][1] = {-ed.x*st, -ed.y*st};
    A[1][0] = { ep.x*st,  ep.y*st};
    A[1][1] = { epd.x*ct, epd.y*ct};
}

// One thread per gate: build the fused 4x4 complex matrix into ws.
__global__ void precompute_gates(const float* __restrict__ conv,
                                 const float* __restrict__ pool,
                                 float2* __restrict__ gates)
{
    int g = threadIdx.x;
    if (g >= NGATES) return;
    cpx M[4][4];
    int l = GL[g], pi = GP[g];
    if (GT[g] == 0) {
        const float* W1 = conv + l*150 + pi*15;
        const float* W2 = conv + l*150 + (pi+1)*15;
        cpx A1[2][2], B1[2][2], A2[2][2], B2[2][2];
        u3m(A1, W1[0],  W1[1],  W1[2]);    // pre  on w1
        u3m(B1, W2[3],  W2[4],  W2[5]);    // pre  on w2
        u3m(A2, W1[9],  W1[10], W1[11]);   // post on w1
        u3m(B2, W2[12], W2[13], W2[14]);   // post on w2
        cpx T[4][4];
        #pragma unroll
        for (int r1=0;r1<2;++r1)
        #pragma unroll
        for (int r2=0;r2<2;++r2)
        #pragma unroll
        for (int c1=0;c1<2;++c1)
        #pragma unroll
        for (int c2=0;c2<2;++c2)
            T[2*r1+r2][2*c1+c2] = cmul(A1[r1][c1], B1[r2][c2]);   // A1⊗B1
        // ZZ(t): diag(e^{-it/2}, e^{it/2}, e^{it/2}, e^{-it/2})
        float tz = W1[6];
        cpx em = cexp_i(-0.5f*tz), ep = cexp_i(0.5f*tz);
        cpx dz[4] = {em, ep, ep, em};
        #pragma unroll
        for (int r=0;r<4;++r)
        #pragma unroll
        for (int c=0;c<4;++c) T[r][c] = cmul(dz[r], T[r][c]);
        // YY(t) = cos I - i sin * YY4 ; (YY4@T) rows: -T3, T2, T1, -T0
        float ty = W1[7]; float cy = cosf(0.5f*ty), sy = sinf(0.5f*ty);
        cpx T2_[4][4];
        #pragma unroll
        for (int c=0;c<4;++c) {
            T2_[0][c] = cadd(cscale(cy,T[0][c]), mulnegi(cscale(-sy, T[3][c])));
            T2_[1][c] = cadd(cscale(cy,T[1][c]), mulnegi(cscale( sy, T[2][c])));
            T2_[2][c] = cadd(cscale(cy,T[2][c]), mulnegi(cscale( sy, T[1][c])));
            T2_[3][c] = cadd(cscale(cy,T[3][c]), mulnegi(cscale(-sy, T[0][c])));
        }
        // XX(t) = cos I - i sin * XX4 ; (XX4@T) rows: T3, T2, T1, T0
        float tx = W1[8]; float cx = cosf(0.5f*tx), sx = sinf(0.5f*tx);
        cpx T3_[4][4];
        #pragma unroll
        for (int c=0;c<4;++c) {
            T3_[0][c] = cadd(cscale(cx,T2_[0][c]), mulnegi(cscale(sx, T2_[3][c])));
            T3_[1][c] = cadd(cscale(cx,T2_[1][c]), mulnegi(cscale(sx, T2_[2][c])));
            T3_[2][c] = cadd(cscale(cx,T2_[2][c]), mulnegi(cscale(sx, T2_[1][c])));
            T3_[3][c] = cadd(cscale(cx,T2_[3][c]), mulnegi(cscale(sx, T2_[0][c])));
        }
        cpx K2[4][4];
        #pragma unroll
        for (int r1=0;r1<2;++r1)
        #pragma unroll
        for (int r2=0;r2<2;++r2)
        #pragma unroll
        for (int c1=0;c1<2;++c1)
        #pragma unroll
        for (int c2=0;c2<2;++c2)
            K2[2*r1+r2][2*c1+c2] = cmul(A2[r1][c1], B2[r2][c2]);   // A2⊗B2
        #pragma unroll
        for (int r=0;r<4;++r)
        #pragma unroll
        for (int c=0;c<4;++c) {
            cpx acc = {0.f, 0.f};
            #pragma unroll
            for (int m=0;m<4;++m) acc = cadd(acc, cmul(K2[r][m], T3_[m][c]));
            M[r][c] = acc;
        }
    } else {
        // CRot(phi, theta, omega), basis |ctrl tgt>, ctrl = high bit
        const float* Pp = pool + l*15 + pi*3;
        float phi = Pp[0], th = Pp[1], om = Pp[2];
        float ct = cosf(0.5f*th), st = sinf(0.5f*th);
        #pragma unroll
        for (int r=0;r<4;++r)
        #pragma unroll
        for (int c=0;c<4;++c) M[r][c] = {0.f, 0.f};
        M[0][0] = {1.f, 0.f};
        M[1][1] = {1.f, 0.f};
        M[2][2] = cscale( ct, cexp_i(-0.5f*(phi+om)));
        M[2][3] = cscale(-st, cexp_i( 0.5f*(phi-om)));
        M[3][2] = cscale( st, cexp_i(-0.5f*(phi-om)));
        M[3][3] = cscale( ct, cexp_i( 0.5f*(phi+om)));
    }
    #pragma unroll
    for (int r=0;r<4;++r)
    #pragma unroll
    for (int c=0;c<4;++c)
        gates[g*16 + r*4 + c] = make_float2(M[r][c].x, M[r][c].y);
}

// One block = one sample. 256 threads, 4 amplitudes/thread, state in LDS.
__global__ __launch_bounds__(256) void hqtcn_sim(
    const float* __restrict__ x,      // (16, 32, 128)
    const float* __restrict__ fc_w,   // (10, 256)
    const float* __restrict__ fc_b,   // (10,)
    const float2* __restrict__ gates, // (23, 16)
    float* __restrict__ out)          // (1936,)
{
    __shared__ float2 st[1024];
    __shared__ float2 gm[NGATES*16];
    __shared__ float  red[64];
    __shared__ float  csh[2][NQ];

    const int t = threadIdx.x;
    const int s = blockIdx.x;
    const int b = s / NWIN, w = s % NWIN;
    const int wave = t >> 6, lane = t & 63;

    // stage gate matrices to LDS
    for (int k = t; k < NGATES*16; k += 256) gm[k] = gates[k];

    // ---- angles: angle[e] = sum_{c,j} x[b,c,w+j] * fc_w[e, c*8+j] + fc_b[e]
    // thread t <-> feature f = t (c = t>>3, j = t&7)
    float xv = x[b*4096 + (t >> 3)*128 + w + (t & 7)];
    #pragma unroll
    for (int e = 0; e < NQ; ++e) {
        float v = xv * fc_w[e*256 + t];
        #pragma unroll
        for (int off = 32; off >= 1; off >>= 1) v += __shfl_xor(v, off);
        if (lane == 0) red[e*4 + wave] = v;
    }
    __syncthreads();
    if (t < NQ) {
        float a = red[t*4+0] + red[t*4+1] + red[t*4+2] + red[t*4+3] + fc_b[t];
        float h = 0.5f * a;
        csh[0][t] = cosf(h);
        csh[1][t] = sinf(h);
    }
    __syncthreads();

    // ---- init product state: amp(i) = prod_q (bit(i,9-q) ? sin : cos)
    float cq[NQ], sq[NQ];
    #pragma unroll
    for (int q = 0; q < NQ; ++q) { cq[q] = csh[0][q]; sq[q] = csh[1][q]; }
    #pragma unroll
    for (int r = 0; r < 4; ++r) {
        int i = 4*t + r;
        float p = 1.f;
        #pragma unroll
        for (int q = 0; q < NQ; ++q)
            p *= ((i >> (9 - q)) & 1) ? sq[q] : cq[q];
        st[i] = make_float2(p, 0.f);
    }

    // ---- 23 two-qubit gates; each thread owns one 4-amplitude group per gate
    #pragma unroll
    for (int g = 0; g < NGATES; ++g) {
        __syncthreads();   // make previous gate's (or init's) writes visible
        const int b1 = 9 - GQ1[g], b2 = 9 - GQ2[g];
        const int lo = (b1 < b2) ? b1 : b2;
        const int hi = (b1 < b2) ? b2 : b1;
        int x1   = ((t  & ~((1 << lo) - 1)) << 1) | (t  & ((1 << lo) - 1));
        int base = ((x1 & ~((1 << hi) - 1)) << 1) | (x1 & ((1 << hi) - 1));
        float2 v0 = st[base];
        float2 v1 = st[base | (1 << b2)];
        float2 v2 = st[base | (1 << b1)];
        float2 v3 = st[base | (1 << b1) | (1 << b2)];
        float2 nv[4];
        #pragma unroll
        for (int k = 0; k < 4; ++k) {
            float re = 0.f, im = 0.f;
            float2 m0 = gm[g*16 + k*4 + 0];
            float2 m1 = gm[g*16 + k*4 + 1];
            float2 m2 = gm[g*16 + k*4 + 2];
            float2 m3 = gm[g*16 + k*4 + 3];
            re += m0.x*v0.x - m0.y*v0.y;  im += m0.x*v0.y + m0.y*v0.x;
            re += m1.x*v1.x - m1.y*v1.y;  im += m1.x*v1.y + m1.y*v1.x;
            re += m2.x*v2.x - m2.y*v2.y;  im += m2.x*v2.y + m2.y*v2.x;
            re += m3.x*v3.x - m3.y*v3.y;  im += m3.x*v3.y + m3.y*v3.x;
            nv[k] = make_float2(re, im);
        }
        st[base]                         = nv[0];
        st[base | (1 << b2)]             = nv[1];
        st[base | (1 << b1)]             = nv[2];
        st[base | (1 << b1) | (1 << b2)] = nv[3];
    }
    __syncthreads();

    // ---- <Z0> = sum_i sign(bit9(i)) |psi_i|^2
    float acc = 0.f;
    #pragma unroll
    for (int r = 0; r < 4; ++r) {
        int i = 4*t + r;
        float2 a = st[i];
        float pr = a.x*a.x + a.y*a.y;
        acc += (i & 512) ? -pr : pr;
    }
    #pragma unroll
    for (int off = 32; off >= 1; off >>= 1) acc += __shfl_xor(acc, off);
    if (lane == 0) red[wave] = acc;
    __syncthreads();
    if (t == 0) out[s] = red[0] + red[1] + red[2] + red[3];
}

extern "C" void kernel_launch(void* const* d_in, const int* in_sizes, int n_in,
                              void* d_out, int out_size, void* d_ws, size_t ws_size,
                              hipStream_t stream) {
    const float* x     = (const float*)d_in[0];
    const float* fc_w  = (const float*)d_in[1];
    const float* fc_b  = (const float*)d_in[2];
    const float* convp = (const float*)d_in[3];
    const float* poolp = (const float*)d_in[4];
    float2* gates = (float2*)d_ws;   // 23*16*8 = 2944 bytes
    float* out = (float*)d_out;

    precompute_gates<<<1, 64, 0, stream>>>(convp, poolp, gates);
    hqtcn_sim<<<16*NWIN, 256, 0, stream>>>(x, fc_w, fc_b, gates, out);
}

// Round 2
// 56.102 us; speedup vs baseline: 1.0988x; 1.0988x over previous
//
#include <hip/hip_runtime.h>

#define NWIN 121
#define NQ 10
#define NGATES 23

// Gate schedule (static: depth=3, wires [0..9] -> [0,2,4,6,8] -> [0,4,8]).
// type 0 = fused conv block (u3⊗u3 · XX·YY·ZZ · u3⊗u3), type 1 = CRot.
static constexpr int GT [NGATES] = {0,0,0,0,0,0,0,0,0, 1,1,1,1,1, 0,0,0,0, 1,1, 0,0, 1};
static constexpr int GL [NGATES] = {0,0,0,0,0,0,0,0,0, 0,0,0,0,0, 1,1,1,1, 1,1, 2,2, 2};
static constexpr int GP [NGATES] = {0,2,4,6,8,1,3,5,7, 0,1,2,3,4, 0,2,1,3, 0,1, 0,1, 0};
static constexpr int GQ1[NGATES] = {0,2,4,6,8,1,3,5,7, 1,3,5,7,9, 0,4,2,6, 2,6, 0,4, 4};
static constexpr int GQ2[NGATES] = {1,3,5,7,9,2,4,6,8, 0,2,4,6,8, 2,6,4,8, 0,4, 4,8, 0};

// Gate bit positions (bit = 9 - qubit), consumed by the sim kernel at runtime.
__device__ const int2 GB[NGATES] = {
    {9,8},{7,6},{5,4},{3,2},{1,0},{8,7},{6,5},{4,3},{2,1},
    {8,9},{6,7},{4,5},{2,3},{0,1},
    {9,7},{5,3},{7,5},{3,1},
    {7,9},{3,5},
    {9,5},{5,1},
    {5,9}
};

struct cpx { float x, y; };
__device__ __forceinline__ cpx cmul(cpx a, cpx b){ return {a.x*b.x - a.y*b.y, a.x*b.y + a.y*b.x}; }
__device__ __forceinline__ cpx cadd(cpx a, cpx b){ return {a.x+b.x, a.y+b.y}; }
__device__ __forceinline__ cpx cscale(float s, cpx a){ return {s*a.x, s*a.y}; }
__device__ __forceinline__ cpx cexp_i(float t){ return {cosf(t), sinf(t)}; }
__device__ __forceinline__ cpx mulnegi(cpx z){ return {z.y, -z.x}; }   // -i*z

__device__ __forceinline__ void u3m(cpx A[2][2], float th, float ph, float de){
    float ct = cosf(0.5f*th), st = sinf(0.5f*th);
    cpx ed  = cexp_i(de);
    cpx ep  = cexp_i(ph);
    cpx epd = cexp_i(ph + de);
    A[0][0] = {ct, 0.f};
    A[0][1] = {-ed.x*st, -ed.y*st};
    A[1][0] = { ep.x*st,  ep.y*st};
    A[1][1] = { epd.x*ct, epd.y*ct};
}

// One thread per gate: build the fused 4x4 complex matrix into ws.
__global__ void precompute_gates(const float* __restrict__ conv,
                                 const float* __restrict__ pool,
                                 float2* __restrict__ gates)
{
    int g = threadIdx.x;
    if (g >= NGATES) return;
    cpx M[4][4];
    int l = GL[g], pi = GP[g];
    if (GT[g] == 0) {
        const float* W1 = conv + l*150 + pi*15;
        const float* W2 = conv + l*150 + (pi+1)*15;
        cpx A1[2][2], B1[2][2], A2[2][2], B2[2][2];
        u3m(A1, W1[0],  W1[1],  W1[2]);    // pre  on w1
        u3m(B1, W2[3],  W2[4],  W2[5]);    // pre  on w2
        u3m(A2, W1[9],  W1[10], W1[11]);   // post on w1
        u3m(B2, W2[12], W2[13], W2[14]);   // post on w2
        cpx T[4][4];
        #pragma unroll
        for (int r1=0;r1<2;++r1)
        #pragma unroll
        for (int r2=0;r2<2;++r2)
        #pragma unroll
        for (int c1=0;c1<2;++c1)
        #pragma unroll
        for (int c2=0;c2<2;++c2)
            T[2*r1+r2][2*c1+c2] = cmul(A1[r1][c1], B1[r2][c2]);   // A1⊗B1
        // ZZ(t): diag(e^{-it/2}, e^{it/2}, e^{it/2}, e^{-it/2})
        float tz = W1[6];
        cpx em = cexp_i(-0.5f*tz), ep = cexp_i(0.5f*tz);
        cpx dz[4] = {em, ep, ep, em};
        #pragma unroll
        for (int r=0;r<4;++r)
        #pragma unroll
        for (int c=0;c<4;++c) T[r][c] = cmul(dz[r], T[r][c]);
        // YY(t) = cos I - i sin * YY4 ; (YY4@T) rows: -T3, T2, T1, -T0
        float ty = W1[7]; float cy = cosf(0.5f*ty), sy = sinf(0.5f*ty);
        cpx T2_[4][4];
        #pragma unroll
        for (int c=0;c<4;++c) {
            T2_[0][c] = cadd(cscale(cy,T[0][c]), mulnegi(cscale(-sy, T[3][c])));
            T2_[1][c] = cadd(cscale(cy,T[1][c]), mulnegi(cscale( sy, T[2][c])));
            T2_[2][c] = cadd(cscale(cy,T[2][c]), mulnegi(cscale( sy, T[1][c])));
            T2_[3][c] = cadd(cscale(cy,T[3][c]), mulnegi(cscale(-sy, T[0][c])));
        }
        // XX(t) = cos I - i sin * XX4 ; (XX4@T) rows: T3, T2, T1, T0
        float tx = W1[8]; float cx = cosf(0.5f*tx), sx = sinf(0.5f*tx);
        cpx T3_[4][4];
        #pragma unroll
        for (int c=0;c<4;++c) {
            T3_[0][c] = cadd(cscale(cx,T2_[0][c]), mulnegi(cscale(sx, T2_[3][c])));
            T3_[1][c] = cadd(cscale(cx,T2_[1][c]), mulnegi(cscale(sx, T2_[2][c])));
            T3_[2][c] = cadd(cscale(cx,T2_[2][c]), mulnegi(cscale(sx, T2_[1][c])));
            T3_[3][c] = cadd(cscale(cx,T2_[3][c]), mulnegi(cscale(sx, T2_[0][c])));
        }
        cpx K2[4][4];
        #pragma unroll
        for (int r1=0;r1<2;++r1)
        #pragma unroll
        for (int r2=0;r2<2;++r2)
        #pragma unroll
        for (int c1=0;c1<2;++c1)
        #pragma unroll
        for (int c2=0;c2<2;++c2)
            K2[2*r1+r2][2*c1+c2] = cmul(A2[r1][c1], B2[r2][c2]);   // A2⊗B2
        #pragma unroll
        for (int r=0;r<4;++r)
        #pragma unroll
        for (int c=0;c<4;++c) {
            cpx acc = {0.f, 0.f};
            #pragma unroll
            for (int m=0;m<4;++m) acc = cadd(acc, cmul(K2[r][m], T3_[m][c]));
            M[r][c] = acc;
        }
    } else {
        // CRot(phi, theta, omega), basis |ctrl tgt>, ctrl = high bit
        const float* Pp = pool + l*15 + pi*3;
        float phi = Pp[0], th = Pp[1], om = Pp[2];
        float ct = cosf(0.5f*th), st = sinf(0.5f*th);
        #pragma unroll
        for (int r=0;r<4;++r)
        #pragma unroll
        for (int c=0;c<4;++c) M[r][c] = {0.f, 0.f};
        M[0][0] = {1.f, 0.f};
        M[1][1] = {1.f, 0.f};
        M[2][2] = cscale( ct, cexp_i(-0.5f*(phi+om)));
        M[2][3] = cscale(-st, cexp_i( 0.5f*(phi-om)));
        M[3][2] = cscale( st, cexp_i(-0.5f*(phi-om)));
        M[3][3] = cscale( ct, cexp_i( 0.5f*(phi+om)));
    }
    #pragma unroll
    for (int r=0;r<4;++r)
    #pragma unroll
    for (int c=0;c<4;++c)
        gates[g*16 + r*4 + c] = make_float2(M[r][c].x, M[r][c].y);
}

// One WAVE (64 lanes) per sample. 16 amplitudes per lane, state in LDS,
// no cross-wave barriers (single-wave block -> __syncthreads is ~free).
__global__ __launch_bounds__(64) void hqtcn_sim(
    const float* __restrict__ x,      // (16, 32, 128)
    const float* __restrict__ fc_w,   // (10, 256)
    const float* __restrict__ fc_b,   // (10,)
    const float2* __restrict__ gates, // (23, 16)
    float* __restrict__ out)          // (1936,)
{
    __shared__ float2 st[1024];

    const int lane = threadIdx.x;     // 0..63
    const int s = blockIdx.x;
    const int b = s / NWIN, w = s % NWIN;

    // ---- angles: angle[e] = sum_{f=0..255} flat[f] * fc_w[e,f] + fc_b[e]
    // lane handles features f = lane + 64*j, j=0..3;  f -> (c = f>>3, j = f&7)
    float xv[4];
    #pragma unroll
    for (int j = 0; j < 4; ++j) {
        int f = lane + 64*j;
        xv[j] = x[b*4096 + (f >> 3)*128 + w + (f & 7)];
    }
    float cq[NQ], sq[NQ];
    #pragma unroll
    for (int e = 0; e < NQ; ++e) {
        float v = 0.f;
        #pragma unroll
        for (int j = 0; j < 4; ++j)
            v = fmaf(xv[j], fc_w[e*256 + lane + 64*j], v);
        #pragma unroll
        for (int off = 32; off >= 1; off >>= 1) v += __shfl_xor(v, off);
        float h = 0.5f * (v + fc_b[e]);      // fc_b: uniform scalar load
        __sincosf(h, &sq[e], &cq[e]);
    }

    // ---- init product state.
    // amp index i = r*64 + lane : lane bits = amp bits 0..5 (qubits 9..4),
    //                             r bits 0..3 = amp bits 6..9 (qubits 3..0)
    float pl = 1.f;
    #pragma unroll
    for (int q = 4; q < NQ; ++q)
        pl *= ((lane >> (9 - q)) & 1) ? sq[q] : cq[q];
    float pA[4], pB[4];
    #pragma unroll
    for (int a = 0; a < 4; ++a) {
        pA[a] = ((a >> 1) ? sq[0] : cq[0]) * ((a & 1) ? sq[1] : cq[1]);
        pB[a] = ((a >> 1) ? sq[2] : cq[2]) * ((a & 1) ? sq[3] : cq[3]);
    }
    #pragma unroll
    for (int r = 0; r < 16; ++r)
        st[r*64 + lane] = make_float2(pl * pA[r >> 2] * pB[r & 3], 0.f);
    __syncthreads();

    // ---- 23 two-qubit gates; lane owns 4 disjoint 4-amplitude groups/gate.
    // Runtime loop (no full unroll) keeps the body I-cache resident; gate
    // matrix reads are uniform -> scalar loads (SGPR-held matrix).
    #pragma unroll 1
    for (int g = 0; g < NGATES; ++g) {
        const int2 bb = GB[g];
        const int b1 = bb.x, b2 = bb.y;
        const int lo = (b1 < b2) ? b1 : b2;
        const int hi = (b1 < b2) ? b2 : b1;
        const int mlo = (1 << lo) - 1;
        const int mhi = (1 << hi) - 1;
        const int o2 = 1 << b2, o1 = 1 << b1;

        float2 m[16];
        #pragma unroll
        for (int k = 0; k < 16; ++k) m[k] = gates[g*16 + k];  // uniform

        #pragma unroll
        for (int k = 0; k < 4; ++k) {
            const int G  = (k << 6) | lane;                    // group id
            const int x1   = ((G  & ~mlo) << 1) | (G  & mlo);
            const int base = ((x1 & ~mhi) << 1) | (x1 & mhi);
            const int i1 = base | o2, i2 = base | o1, i3 = base | o1 | o2;
            float2 v0 = st[base], v1 = st[i1], v2 = st[i2], v3 = st[i3];
            float2 nv[4];
            #pragma unroll
            for (int r = 0; r < 4; ++r) {
                float2 m0 = m[r*4+0], m1 = m[r*4+1], m2 = m[r*4+2], m3 = m[r*4+3];
                float re, im;
                re  = m0.x*v0.x - m0.y*v0.y;  im  = m0.x*v0.y + m0.y*v0.x;
                re += m1.x*v1.x - m1.y*v1.y;  im += m1.x*v1.y + m1.y*v1.x;
                re += m2.x*v2.x - m2.y*v2.y;  im += m2.x*v2.y + m2.y*v2.x;
                re += m3.x*v3.x - m3.y*v3.y;  im += m3.x*v3.y + m3.y*v3.x;
                nv[r] = make_float2(re, im);
            }
            st[base] = nv[0]; st[i1] = nv[1]; st[i2] = nv[2]; st[i3] = nv[3];
        }
        __syncthreads();   // single-wave block: just an ordering fence
    }

    // ---- <Z0> = sum_i sign(bit9(i)) |psi_i|^2 ;  bit9(i) = bit3(r)
    float accp = 0.f, accm = 0.f;
    #pragma unroll
    for (int r = 0; r < 16; ++r) {
        float2 a = st[r*64 + lane];
        float p2 = fmaf(a.x, a.x, a.y*a.y);
        if (r < 8) accp += p2; else accm += p2;
    }
    float acc = accp - accm;
    #pragma unroll
    for (int off = 32; off >= 1; off >>= 1) acc += __shfl_xor(acc, off);
    if (lane == 0) out[s] = acc;
}

extern "C" void kernel_launch(void* const* d_in, const int* in_sizes, int n_in,
                              void* d_out, int out_size, void* d_ws, size_t ws_size,
                              hipStream_t stream) {
    const float* x     = (const float*)d_in[0];
    const float* fc_w  = (const float*)d_in[1];
    const float* fc_b  = (const float*)d_in[2];
    const float* convp = (const float*)d_in[3];
    const float* poolp = (const float*)d_in[4];
    float2* gates = (float2*)d_ws;   // 23*16*8 = 2944 bytes
    float* out = (float*)d_out;

    precompute_gates<<<1, 64, 0, stream>>>(convp, poolp, gates);
    hqtcn_sim<<<16*NWIN, 64, 0, stream>>>(x, fc_w, fc_b, gates, out);
}

// Round 3
// 32.508 us; speedup vs baseline: 1.8963x; 1.7258x over previous
//
#include <hip/hip_runtime.h>

#define NWIN 121
#define NQ 10
#define NGATES 23

typedef float v2f __attribute__((ext_vector_type(2)));

// Gate schedule (static: depth=3, wires [0..9] -> [0,2,4,6,8] -> [0,4,8]).
// type 0 = fused conv block (u3⊗u3 · XX·YY·ZZ · u3⊗u3), type 1 = CRot.
static constexpr int GT [NGATES] = {0,0,0,0,0,0,0,0,0, 1,1,1,1,1, 0,0,0,0, 1,1, 0,0, 1};
static constexpr int GL [NGATES] = {0,0,0,0,0,0,0,0,0, 0,0,0,0,0, 1,1,1,1, 1,1, 2,2, 2};
static constexpr int GP [NGATES] = {0,2,4,6,8,1,3,5,7, 0,1,2,3,4, 0,2,1,3, 0,1, 0,1, 0};

// ---- register-resident phase schedule -------------------------------------
// Logical amp bit = 9 - qubit. Per phase: 4 logical bits live in the register
// index (REGB[ph][k] = logical bit at reg-index bit k), 6 in the lane index
// (LANEB[ph][j] = logical bit at lane bit j). Between phases: LDS re-permute
// with XOR swizzle slot = L ^ hswz(perm, L) (bank bits lane-driven both sides).
__host__ __device__ constexpr int REGB[7][4] = {
    {6,7,8,9},{4,5,6,7},{0,1,2,3},{2,3,4,5},{1,3,7,9},{3,5,7,9},{1,5,9,8}};
__host__ __device__ constexpr int LANEB[7][6] = {
    {0,1,2,3,4,5},{0,1,2,3,8,9},{4,5,6,7,8,9},{0,1,6,7,8,9},
    {0,2,4,5,6,8},{0,1,2,4,6,8},{0,2,3,4,6,7}};

__host__ __device__ constexpr int hswz(int p, int L){
    return p==0 ? 0
         : p==1 ? ((L>>4)&15)
         : p==2 ? ((L>>6)&15)
         : p==3 ? ((((L>>6)&1)<<3) | (((L>>8)&1)<<1) | (((L>>9)&1)<<2))
         :        ((((L>>4)&1)<<3) | (((L>>6)&1)<<1));   // perms 4 and 5
}
__host__ __device__ constexpr int offsL(int ph, int r){
    int o = 0;
    for (int k=0;k<4;++k) if ((r>>k)&1) o |= 1<<REGB[ph][k];
    return o;
}

struct cpx { float x, y; };
__device__ __forceinline__ cpx cmul(cpx a, cpx b){ return {a.x*b.x - a.y*b.y, a.x*b.y + a.y*b.x}; }
__device__ __forceinline__ cpx cadd(cpx a, cpx b){ return {a.x+b.x, a.y+b.y}; }
__device__ __forceinline__ cpx cscale(float s, cpx a){ return {s*a.x, s*a.y}; }
__device__ __forceinline__ cpx cexp_i(float t){ return {cosf(t), sinf(t)}; }
__device__ __forceinline__ cpx mulnegi(cpx z){ return {z.y, -z.x}; }   // -i*z

__device__ __forceinline__ void u3m(cpx A[2][2], float th, float ph, float de){
    float ct = cosf(0.5f*th), st = sinf(0.5f*th);
    cpx ed  = cexp_i(de);
    cpx ep  = cexp_i(ph);
    cpx epd = cexp_i(ph + de);
    A[0][0] = {ct, 0.f};
    A[0][1] = {-ed.x*st, -ed.y*st};
    A[1][0] = { ep.x*st,  ep.y*st};
    A[1][1] = { epd.x*ct, epd.y*ct};
}

// One thread per gate: build the fused 4x4 complex matrix into ws.
__global__ void precompute_gates(const float* __restrict__ conv,
                                 const float* __restrict__ pool,
                                 float2* __restrict__ gates)
{
    int g = threadIdx.x;
    if (g >= NGATES) return;
    cpx M[4][4];
    int l = GL[g], pi = GP[g];
    if (GT[g] == 0) {
        const float* W1 = conv + l*150 + pi*15;
        const float* W2 = conv + l*150 + (pi+1)*15;
        cpx A1[2][2], B1[2][2], A2[2][2], B2[2][2];
        u3m(A1, W1[0],  W1[1],  W1[2]);
        u3m(B1, W2[3],  W2[4],  W2[5]);
        u3m(A2, W1[9],  W1[10], W1[11]);
        u3m(B2, W2[12], W2[13], W2[14]);
        cpx T[4][4];
        #pragma unroll
        for (int r1=0;r1<2;++r1)
        #pragma unroll
        for (int r2=0;r2<2;++r2)
        #pragma unroll
        for (int c1=0;c1<2;++c1)
        #pragma unroll
        for (int c2=0;c2<2;++c2)
            T[2*r1+r2][2*c1+c2] = cmul(A1[r1][c1], B1[r2][c2]);
        float tz = W1[6];
        cpx em = cexp_i(-0.5f*tz), ep = cexp_i(0.5f*tz);
        cpx dz[4] = {em, ep, ep, em};
        #pragma unroll
        for (int r=0;r<4;++r)
        #pragma unroll
        for (int c=0;c<4;++c) T[r][c] = cmul(dz[r], T[r][c]);
        float ty = W1[7]; float cy = cosf(0.5f*ty), sy = sinf(0.5f*ty);
        cpx T2_[4][4];
        #pragma unroll
        for (int c=0;c<4;++c) {
            T2_[0][c] = cadd(cscale(cy,T[0][c]), mulnegi(cscale(-sy, T[3][c])));
            T2_[1][c] = cadd(cscale(cy,T[1][c]), mulnegi(cscale( sy, T[2][c])));
            T2_[2][c] = cadd(cscale(cy,T[2][c]), mulnegi(cscale( sy, T[1][c])));
            T2_[3][c] = cadd(cscale(cy,T[3][c]), mulnegi(cscale(-sy, T[0][c])));
        }
        float tx = W1[8]; float cx = cosf(0.5f*tx), sx = sinf(0.5f*tx);
        cpx T3_[4][4];
        #pragma unroll
        for (int c=0;c<4;++c) {
            T3_[0][c] = cadd(cscale(cx,T2_[0][c]), mulnegi(cscale(sx, T2_[3][c])));
            T3_[1][c] = cadd(cscale(cx,T2_[1][c]), mulnegi(cscale(sx, T2_[2][c])));
            T3_[2][c] = cadd(cscale(cx,T2_[2][c]), mulnegi(cscale(sx, T2_[1][c])));
            T3_[3][c] = cadd(cscale(cx,T2_[3][c]), mulnegi(cscale(sx, T2_[0][c])));
        }
        cpx K2[4][4];
        #pragma unroll
        for (int r1=0;r1<2;++r1)
        #pragma unroll
        for (int r2=0;r2<2;++r2)
        #pragma unroll
        for (int c1=0;c1<2;++c1)
        #pragma unroll
        for (int c2=0;c2<2;++c2)
            K2[2*r1+r2][2*c1+c2] = cmul(A2[r1][c1], B2[r2][c2]);
        #pragma unroll
        for (int r=0;r<4;++r)
        #pragma unroll
        for (int c=0;c<4;++c) {
            cpx acc = {0.f, 0.f};
            #pragma unroll
            for (int m=0;m<4;++m) acc = cadd(acc, cmul(K2[r][m], T3_[m][c]));
            M[r][c] = acc;
        }
    } else {
        const float* Pp = pool + l*15 + pi*3;
        float phi = Pp[0], th = Pp[1], om = Pp[2];
        float ct = cosf(0.5f*th), st = sinf(0.5f*th);
        #pragma unroll
        for (int r=0;r<4;++r)
        #pragma unroll
        for (int c=0;c<4;++c) M[r][c] = {0.f, 0.f};
        M[0][0] = {1.f, 0.f};
        M[1][1] = {1.f, 0.f};
        M[2][2] = cscale( ct, cexp_i(-0.5f*(phi+om)));
        M[2][3] = cscale(-st, cexp_i( 0.5f*(phi-om)));
        M[3][2] = cscale( st, cexp_i(-0.5f*(phi-om)));
        M[3][3] = cscale( ct, cexp_i( 0.5f*(phi+om)));
    }
    #pragma unroll
    for (int r=0;r<4;++r)
    #pragma unroll
    for (int c=0;c<4;++c)
        gates[g*16 + r*4 + c] = make_float2(M[r][c].x, M[r][c].y);
}

// ---- sim kernel helpers ----------------------------------------------------

// complex fused-multiply-add: acc += m * v  (2x v_pk_fma_f32 expected)
__device__ __forceinline__ v2f cfma(v2f m, v2f v, v2f acc) {
    v2f sw = {v.y, v.x};
    v2f my = {-m.y, m.y};
    v2f t = __builtin_elementwise_fma(my, sw, acc);
    v2f mx = {m.x, m.x};
    return __builtin_elementwise_fma(mx, v, t);
}

// dense 4x4 complex gate on register bits P1 (b1) and P2 (b2); k = 2*bit_b1 + bit_b2
template<int P1, int P2>
__device__ __forceinline__ void gate4(v2f (&st)[16], const float2* __restrict__ g) {
    v2f m[16];
    #pragma unroll
    for (int k = 0; k < 16; ++k) { float2 t = g[k]; m[k] = (v2f){t.x, t.y}; }
    constexpr int M1 = 1 << P1, M2 = 1 << P2;
    #pragma unroll
    for (int b = 0; b < 16; ++b) {
        if (b & (M1 | M2)) continue;
        v2f v0 = st[b], v1 = st[b|M2], v2 = st[b|M1], v3 = st[b|M1|M2];
        #pragma unroll
        for (int row = 0; row < 4; ++row) {
            v2f acc = cfma(m[row*4+0], v0, (v2f){0.f, 0.f});
            acc = cfma(m[row*4+1], v1, acc);
            acc = cfma(m[row*4+2], v2, acc);
            acc = cfma(m[row*4+3], v3, acc);
            st[b | ((row>>1) ? M1 : 0) | ((row&1) ? M2 : 0)] = acc;
        }
    }
}

// CRot: identity on ctrl=0 half; active 2x2 block on ctrl(P1)=1 rows.
template<int P1, int P2>
__device__ __forceinline__ void crot4(v2f (&st)[16], const float2* __restrict__ g) {
    float2 t;
    t = g[10]; v2f m22 = {t.x, t.y};
    t = g[11]; v2f m23 = {t.x, t.y};
    t = g[14]; v2f m32 = {t.x, t.y};
    t = g[15]; v2f m33 = {t.x, t.y};
    constexpr int M1 = 1 << P1, M2 = 1 << P2;
    #pragma unroll
    for (int b = 0; b < 16; ++b) {
        if (!(b & M1) || (b & M2)) continue;   // ctrl=1, tgt=0 bases
        v2f v2_ = st[b], v3_ = st[b|M2];
        st[b]    = cfma(m23, v3_, cfma(m22, v2_, (v2f){0.f,0.f}));
        st[b|M2] = cfma(m33, v3_, cfma(m32, v2_, (v2f){0.f,0.f}));
    }
}

template<int PH>
__device__ __forceinline__ int base_of(int lane) {
    int b = 0;
    #pragma unroll
    for (int j = 0; j < 6; ++j) b |= ((lane >> j) & 1) << LANEB[PH][j];
    return b;
}

// LDS re-permute from phase PERM's mapping to phase PERM+1's mapping.
template<int PERM>
__device__ __forceinline__ void permute(v2f (&st)[16], char* lds, int lane) {
    int bw0 = base_of<PERM>(lane);
    int bw = (bw0 ^ hswz(PERM, bw0)) << 3;
    #pragma unroll
    for (int r = 0; r < 16; ++r) {
        const int o = offsL(PERM, r);
        const int C = (o ^ hswz(PERM, o)) << 3;
        *reinterpret_cast<v2f*>(lds + (bw ^ C)) = st[r];
    }
    __syncthreads();
    int br0 = base_of<PERM+1>(lane);
    int br = (br0 ^ hswz(PERM, br0)) << 3;
    #pragma unroll
    for (int r = 0; r < 16; ++r) {
        const int o = offsL(PERM+1, r);
        const int C = (o ^ hswz(PERM, o)) << 3;
        st[r] = *reinterpret_cast<const v2f*>(lds + (br ^ C));
    }
    __syncthreads();
}

// One WAVE (64 lanes) per sample. 16 amps per lane IN REGISTERS; gates run
// in-register over 7 static phases; 6 LDS permutes move qubit bits between
// lane-index and register-index.
__global__ __launch_bounds__(64) void hqtcn_sim(
    const float* __restrict__ x,      // (16, 32, 128)
    const float* __restrict__ fc_w,   // (10, 256)
    const float* __restrict__ fc_b,   // (10,)
    const float2* __restrict__ gates, // (23, 16)
    float* __restrict__ out)          // (1936,)
{
    __shared__ float2 buf[1024];      // 8 KB permute buffer
    char* lds = reinterpret_cast<char*>(buf);

    const int lane = threadIdx.x;
    const int s = blockIdx.x;
    const int b = s / NWIN, w = s % NWIN;

    // ---- angles
    float xv[4];
    #pragma unroll
    for (int j = 0; j < 4; ++j) {
        int f = lane + 64*j;
        xv[j] = x[b*4096 + (f >> 3)*128 + w + (f & 7)];
    }
    float cq[NQ], sq[NQ];
    #pragma unroll
    for (int e = 0; e < NQ; ++e) {
        float v = 0.f;
        #pragma unroll
        for (int j = 0; j < 4; ++j)
            v = fmaf(xv[j], fc_w[e*256 + lane + 64*j], v);
        #pragma unroll
        for (int off = 32; off >= 1; off >>= 1) v += __shfl_xor(v, off);
        float h = 0.5f * (v + fc_b[e]);
        __sincosf(h, &sq[e], &cq[e]);
    }

    // ---- init product state in registers with phase-0 mapping:
    // L = lane | (r<<6); lane bits = qubits 9..4, r bits = qubits 3..0.
    float pl = 1.f;
    #pragma unroll
    for (int q = 4; q < NQ; ++q)
        pl *= ((lane >> (9 - q)) & 1) ? sq[q] : cq[q];
    float pA[4], pB[4];
    #pragma unroll
    for (int a = 0; a < 4; ++a) {
        pA[a] = ((a >> 1) ? sq[0] : cq[0]) * ((a & 1) ? sq[1] : cq[1]);
        pB[a] = ((a >> 1) ? sq[2] : cq[2]) * ((a & 1) ? sq[3] : cq[3]);
    }
    v2f st[16];
    #pragma unroll
    for (int r = 0; r < 16; ++r)
        st[r] = (v2f){pl * pA[r >> 2] * pB[r & 3], 0.f};

    const float2* gm = gates;

    // Phase 0: reg bits {6,7,8,9}
    gate4<3,2>(st, gm + 0*16);    // g0  {9,8}
    gate4<1,0>(st, gm + 1*16);    // g1  {7,6}
    gate4<2,1>(st, gm + 5*16);    // g5  {8,7}
    crot4<2,3>(st, gm + 9*16);    // g9  {8,9}
    permute<0>(st, lds, lane);
    // Phase 1: reg bits {4,5,6,7}
    gate4<1,0>(st, gm + 2*16);    // g2  {5,4}
    gate4<2,1>(st, gm + 6*16);    // g6  {6,5}
    crot4<2,3>(st, gm + 10*16);   // g10 {6,7}
    permute<1>(st, lds, lane);
    // Phase 2: reg bits {0,1,2,3}
    gate4<3,2>(st, gm + 3*16);    // g3  {3,2}
    gate4<1,0>(st, gm + 4*16);    // g4  {1,0}
    gate4<2,1>(st, gm + 8*16);    // g8  {2,1}
    crot4<0,1>(st, gm + 13*16);   // g13 {0,1}
    permute<2>(st, lds, lane);
    // Phase 3: reg bits {2,3,4,5}
    gate4<2,1>(st, gm + 7*16);    // g7  {4,3}
    crot4<2,3>(st, gm + 11*16);   // g11 {4,5}
    crot4<0,1>(st, gm + 12*16);   // g12 {2,3}
    gate4<3,1>(st, gm + 15*16);   // g15 {5,3}
    permute<3>(st, lds, lane);
    // Phase 4: reg bits {1,3,7,9}
    gate4<3,2>(st, gm + 14*16);   // g14 {9,7}
    gate4<1,0>(st, gm + 17*16);   // g17 {3,1}
    permute<4>(st, lds, lane);
    // Phase 5: reg bits {3,5,7,9}
    gate4<2,1>(st, gm + 16*16);   // g16 {7,5}
    crot4<2,3>(st, gm + 18*16);   // g18 {7,9}
    crot4<0,1>(st, gm + 19*16);   // g19 {3,5}
    permute<5>(st, lds, lane);
    // Phase 6: reg bits {1,5,9,8}
    gate4<2,1>(st, gm + 20*16);   // g20 {9,5}
    gate4<1,0>(st, gm + 21*16);   // g21 {5,1}
    crot4<1,2>(st, gm + 22*16);   // g22 {5,9}

    // ---- <Z0>: logical bit 9 sits at reg-index bit 2 in phase 6.
    float accp = 0.f, accm = 0.f;
    #pragma unroll
    for (int r = 0; r < 16; ++r) {
        v2f a = st[r];
        float p2 = fmaf(a.x, a.x, a.y*a.y);
        if ((r >> 2) & 1) accm += p2; else accp += p2;
    }
    float acc = accp - accm;
    #pragma unroll
    for (int off = 32; off >= 1; off >>= 1) acc += __shfl_xor(acc, off);
    if (lane == 0) out[s] = acc;
}

extern "C" void kernel_launch(void* const* d_in, const int* in_sizes, int n_in,
                              void* d_out, int out_size, void* d_ws, size_t ws_size,
                              hipStream_t stream) {
    const float* x     = (const float*)d_in[0];
    const float* fc_w  = (const float*)d_in[1];
    const float* fc_b  = (const float*)d_in[2];
    const float* convp = (const float*)d_in[3];
    const float* poolp = (const float*)d_in[4];
    float2* gates = (float2*)d_ws;   // 23*16*8 = 2944 bytes
    float* out = (float*)d_out;

    precompute_gates<<<1, 64, 0, stream>>>(convp, poolp, gates);
    hqtcn_sim<<<16*NWIN, 64, 0, stream>>>(x, fc_w, fc_b, gates, out);
}

// Round 4
// 31.474 us; speedup vs baseline: 1.9586x; 1.0328x over previous
//
#include <hip/hip_runtime.h>

#define NWIN 121
#define NQ 10
#define NGATES 23

typedef float v2f __attribute__((ext_vector_type(2)));

// Gate schedule (static: depth=3, wires [0..9] -> [0,2,4,6,8] -> [0,4,8]).
// type 0 = fused conv block (u3⊗u3 · XX·YY·ZZ · u3⊗u3), type 1 = CRot.
static constexpr int GT [NGATES] = {0,0,0,0,0,0,0,0,0, 1,1,1,1,1, 0,0,0,0, 1,1, 0,0, 1};
static constexpr int GL [NGATES] = {0,0,0,0,0,0,0,0,0, 0,0,0,0,0, 1,1,1,1, 1,1, 2,2, 2};
static constexpr int GP [NGATES] = {0,2,4,6,8,1,3,5,7, 0,1,2,3,4, 0,2,1,3, 0,1, 0,1, 0};

// ---- register-resident phase schedule (g0..g4 absorbed into init) ---------
// Logical amp bit = 9 - qubit. Phases A..F (0..5): 4 logical bits in the
// register index (REGB[ph][k] = logical bit at reg-index bit k), 6 in the
// lane index. 5 LDS permutes between phases, XOR-swizzled so the 4 slot
// low bits are rank-4 lane-driven on BOTH write and read sides.
__host__ __device__ constexpr int REGB[6][4] = {
    {5,6,7,8},{1,2,3,4},{4,5,8,9},{0,1,3,5},{3,5,7,9},{0,1,5,9}};
__host__ __device__ constexpr int LANEB[6][6] = {
    {0,1,2,3,4,9},{0,5,6,7,8,9},{0,1,2,3,6,7},
    {2,4,6,7,8,9},{0,1,2,4,6,8},{2,3,4,6,7,8}};

__host__ __device__ constexpr int hswz(int p, int L){
    return p==0 ? ((((L>>5)&1)<<1)|(((L>>6)&1)<<2)|(((L>>7)&1)<<3))
         : p==1 ? ((((L>>6)&1)<<1)|(((L>>7)&1)<<2)|(((L>>8)&1)<<3))
         : p==2 ? (((L>>4)&1)|(((L>>6)&1)<<1)|(((L>>7)&1)<<3))
         :        (((L>>4)&1)|(((L>>6)&1)<<1)|(((L>>8)&1)<<3));  // p=3,4
}
__host__ __device__ constexpr int offsL(int ph, int r){
    int o = 0;
    for (int k=0;k<4;++k) if ((r>>k)&1) o |= 1<<REGB[ph][k];
    return o;
}

struct cpx { float x, y; };
__device__ __forceinline__ cpx cmul(cpx a, cpx b){ return {a.x*b.x - a.y*b.y, a.x*b.y + a.y*b.x}; }
__device__ __forceinline__ cpx cadd(cpx a, cpx b){ return {a.x+b.x, a.y+b.y}; }
__device__ __forceinline__ cpx cscale(float s, cpx a){ return {s*a.x, s*a.y}; }
__device__ __forceinline__ cpx cexp_i(float t){ return {cosf(t), sinf(t)}; }
__device__ __forceinline__ cpx mulnegi(cpx z){ return {z.y, -z.x}; }   // -i*z

__device__ __forceinline__ void u3m(cpx A[2][2], float th, float ph, float de){
    float ct = cosf(0.5f*th), st = sinf(0.5f*th);
    cpx ed  = cexp_i(de);
    cpx ep  = cexp_i(ph);
    cpx epd = cexp_i(ph + de);
    A[0][0] = {ct, 0.f};
    A[0][1] = {-ed.x*st, -ed.y*st};
    A[1][0] = { ep.x*st,  ep.y*st};
    A[1][1] = { epd.x*ct, epd.y*ct};
}

// One thread per gate: build the fused 4x4 complex matrix into ws.
__global__ void precompute_gates(const float* __restrict__ conv,
                                 const float* __restrict__ pool,
                                 float2* __restrict__ gates)
{
    int g = threadIdx.x;
    if (g >= NGATES) return;
    cpx M[4][4];
    int l = GL[g], pi = GP[g];
    if (GT[g] == 0) {
        const float* W1 = conv + l*150 + pi*15;
        const float* W2 = conv + l*150 + (pi+1)*15;
        cpx A1[2][2], B1[2][2], A2[2][2], B2[2][2];
        u3m(A1, W1[0],  W1[1],  W1[2]);
        u3m(B1, W2[3],  W2[4],  W2[5]);
        u3m(A2, W1[9],  W1[10], W1[11]);
        u3m(B2, W2[12], W2[13], W2[14]);
        cpx T[4][4];
        #pragma unroll
        for (int r1=0;r1<2;++r1)
        #pragma unroll
        for (int r2=0;r2<2;++r2)
        #pragma unroll
        for (int c1=0;c1<2;++c1)
        #pragma unroll
        for (int c2=0;c2<2;++c2)
            T[2*r1+r2][2*c1+c2] = cmul(A1[r1][c1], B1[r2][c2]);
        float tz = W1[6];
        cpx em = cexp_i(-0.5f*tz), ep = cexp_i(0.5f*tz);
        cpx dz[4] = {em, ep, ep, em};
        #pragma unroll
        for (int r=0;r<4;++r)
        #pragma unroll
        for (int c=0;c<4;++c) T[r][c] = cmul(dz[r], T[r][c]);
        float ty = W1[7]; float cy = cosf(0.5f*ty), sy = sinf(0.5f*ty);
        cpx T2_[4][4];
        #pragma unroll
        for (int c=0;c<4;++c) {
            T2_[0][c] = cadd(cscale(cy,T[0][c]), mulnegi(cscale(-sy, T[3][c])));
            T2_[1][c] = cadd(cscale(cy,T[1][c]), mulnegi(cscale( sy, T[2][c])));
            T2_[2][c] = cadd(cscale(cy,T[2][c]), mulnegi(cscale( sy, T[1][c])));
            T2_[3][c] = cadd(cscale(cy,T[3][c]), mulnegi(cscale(-sy, T[0][c])));
        }
        float tx = W1[8]; float cx = cosf(0.5f*tx), sx = sinf(0.5f*tx);
        cpx T3_[4][4];
        #pragma unroll
        for (int c=0;c<4;++c) {
            T3_[0][c] = cadd(cscale(cx,T2_[0][c]), mulnegi(cscale(sx, T2_[3][c])));
            T3_[1][c] = cadd(cscale(cx,T2_[1][c]), mulnegi(cscale(sx, T2_[2][c])));
            T3_[2][c] = cadd(cscale(cx,T2_[2][c]), mulnegi(cscale(sx, T2_[1][c])));
            T3_[3][c] = cadd(cscale(cx,T2_[3][c]), mulnegi(cscale(sx, T2_[0][c])));
        }
        cpx K2[4][4];
        #pragma unroll
        for (int r1=0;r1<2;++r1)
        #pragma unroll
        for (int r2=0;r2<2;++r2)
        #pragma unroll
        for (int c1=0;c1<2;++c1)
        #pragma unroll
        for (int c2=0;c2<2;++c2)
            K2[2*r1+r2][2*c1+c2] = cmul(A2[r1][c1], B2[r2][c2]);
        #pragma unroll
        for (int r=0;r<4;++r)
        #pragma unroll
        for (int c=0;c<4;++c) {
            cpx acc = {0.f, 0.f};
            #pragma unroll
            for (int m=0;m<4;++m) acc = cadd(acc, cmul(K2[r][m], T3_[m][c]));
            M[r][c] = acc;
        }
    } else {
        const float* Pp = pool + l*15 + pi*3;
        float phi = Pp[0], th = Pp[1], om = Pp[2];
        float ct = cosf(0.5f*th), st = sinf(0.5f*th);
        #pragma unroll
        for (int r=0;r<4;++r)
        #pragma unroll
        for (int c=0;c<4;++c) M[r][c] = {0.f, 0.f};
        M[0][0] = {1.f, 0.f};
        M[1][1] = {1.f, 0.f};
        M[2][2] = cscale( ct, cexp_i(-0.5f*(phi+om)));
        M[2][3] = cscale(-st, cexp_i( 0.5f*(phi-om)));
        M[3][2] = cscale( st, cexp_i(-0.5f*(phi-om)));
        M[3][3] = cscale( ct, cexp_i( 0.5f*(phi+om)));
    }
    #pragma unroll
    for (int r=0;r<4;++r)
    #pragma unroll
    for (int c=0;c<4;++c)
        gates[g*16 + r*4 + c] = make_float2(M[r][c].x, M[r][c].y);
}

// ---- sim kernel helpers ----------------------------------------------------

// complex fused-multiply-add: acc += m * v  (2x v_pk_fma_f32 expected)
__device__ __forceinline__ v2f cfma(v2f m, v2f v, v2f acc) {
    v2f sw = {v.y, v.x};
    v2f my = {-m.y, m.y};
    v2f t = __builtin_elementwise_fma(my, sw, acc);
    v2f mx = {m.x, m.x};
    return __builtin_elementwise_fma(mx, v, t);
}
__device__ __forceinline__ v2f cmulv(v2f a, v2f b) { return cfma(a, b, (v2f){0.f,0.f}); }
__device__ __forceinline__ v2f vsel(int c, v2f a, v2f b) {
    return (v2f){ c ? a.x : b.x, c ? a.y : b.y };
}

// dense 4x4 complex gate on register bits P1,P2; basis k = 2*bit_P1 + bit_P2
template<int P1, int P2>
__device__ __forceinline__ void gate4(v2f (&st)[16], const float2* __restrict__ g) {
    v2f m[16];
    #pragma unroll
    for (int k = 0; k < 16; ++k) { float2 t = g[k]; m[k] = (v2f){t.x, t.y}; }
    constexpr int M1 = 1 << P1, M2 = 1 << P2;
    #pragma unroll
    for (int b = 0; b < 16; ++b) {
        if (b & (M1 | M2)) continue;
        v2f v0 = st[b], v1 = st[b|M2], v2 = st[b|M1], v3 = st[b|M1|M2];
        #pragma unroll
        for (int row = 0; row < 4; ++row) {
            v2f acc = cfma(m[row*4+0], v0, (v2f){0.f, 0.f});
            acc = cfma(m[row*4+1], v1, acc);
            acc = cfma(m[row*4+2], v2, acc);
            acc = cfma(m[row*4+3], v3, acc);
            st[b | ((row>>1) ? M1 : 0) | ((row&1) ? M2 : 0)] = acc;
        }
    }
}

// CRot: identity on ctrl=0 half; active 2x2 block on ctrl(P1)=1 rows.
template<int P1, int P2>
__device__ __forceinline__ void crot4(v2f (&st)[16], const float2* __restrict__ g) {
    float2 t;
    t = g[10]; v2f m22 = {t.x, t.y};
    t = g[11]; v2f m23 = {t.x, t.y};
    t = g[14]; v2f m32 = {t.x, t.y};
    t = g[15]; v2f m33 = {t.x, t.y};
    constexpr int M1 = 1 << P1, M2 = 1 << P2;
    #pragma unroll
    for (int b = 0; b < 16; ++b) {
        if (!(b & M1) || (b & M2)) continue;   // ctrl=1, tgt=0 bases
        v2f v2_ = st[b], v3_ = st[b|M2];
        st[b]    = cfma(m23, v3_, cfma(m22, v2_, (v2f){0.f,0.f}));
        st[b|M2] = cfma(m33, v3_, cfma(m32, v2_, (v2f){0.f,0.f}));
    }
}

template<int PH>
__device__ __forceinline__ int base_of(int lane) {
    int b = 0;
    #pragma unroll
    for (int j = 0; j < 6; ++j) b |= ((lane >> j) & 1) << LANEB[PH][j];
    return b;
}

// LDS re-permute from phase PERM's mapping to phase PERM+1's mapping.
template<int PERM>
__device__ __forceinline__ void permute(v2f (&st)[16], char* lds, int lane) {
    int bw0 = base_of<PERM>(lane);
    int bw = (bw0 ^ hswz(PERM, bw0)) << 3;
    #pragma unroll
    for (int r = 0; r < 16; ++r) {
        const int o = offsL(PERM, r);
        const int C = (o ^ hswz(PERM, o)) << 3;
        *reinterpret_cast<v2f*>(lds + (bw ^ C)) = st[r];
    }
    __syncthreads();
    int br0 = base_of<PERM+1>(lane);
    int br = (br0 ^ hswz(PERM, br0)) << 3;
    #pragma unroll
    for (int r = 0; r < 16; ++r) {
        const int o = offsL(PERM+1, r);
        const int C = (o ^ hswz(PERM, o)) << 3;
        st[r] = *reinterpret_cast<const v2f*>(lds + (br ^ C));
    }
    __syncthreads();
}

// One WAVE per sample; 16 amps/lane in registers. g0..g4 are fused into the
// initial product state (outer product of five gate-transformed pair vectors);
// remaining 18 gates run in-register over 6 phases with 5 LDS permutes.
__global__ __launch_bounds__(64) void hqtcn_sim(
    const float* __restrict__ x,      // (16, 32, 128)
    const float* __restrict__ fc_w,   // (10, 256)
    const float* __restrict__ fc_b,   // (10,)
    const float2* __restrict__ gates, // (23, 16)
    float* __restrict__ out)          // (1936,)
{
    __shared__ float2 buf[1024];      // 8 KB permute buffer
    char* lds = reinterpret_cast<char*>(buf);

    const int lane = threadIdx.x;
    const int s = blockIdx.x;
    const int b = s / NWIN, w = s % NWIN;

    // ---- angles
    float xv[4];
    #pragma unroll
    for (int j = 0; j < 4; ++j) {
        int f = lane + 64*j;
        xv[j] = x[b*4096 + (f >> 3)*128 + w + (f & 7)];
    }
    float cq[NQ], sq[NQ];
    #pragma unroll
    for (int e = 0; e < NQ; ++e) {
        float v = 0.f;
        #pragma unroll
        for (int j = 0; j < 4; ++j)
            v = fmaf(xv[j], fc_w[e*256 + lane + 64*j], v);
        #pragma unroll
        for (int off = 32; off >= 1; off >>= 1) v += __shfl_xor(v, off);
        float h = 0.5f * (v + fc_b[e]);
        __sincosf(h, &sq[e], &cq[e]);
    }

    // ---- init: apply g0..g4 analytically. W[p] = G_p @ [cc',cs',sc',ss']
    // for qubit pair (2p, 2p+1); state = outer product of the five W vectors.
    v2f W[5][4];
    #pragma unroll
    for (int p = 0; p < 5; ++p) {
        float ca = cq[2*p], sa = sq[2*p], cb = cq[2*p+1], sb = sq[2*p+1];
        float u0 = ca*cb, u1 = ca*sb, u2 = sa*cb, u3_ = sa*sb;
        const float2* G = gates + p*16;
        #pragma unroll
        for (int i = 0; i < 4; ++i) {
            float2 g0 = G[i*4+0], g1 = G[i*4+1], g2 = G[i*4+2], g3 = G[i*4+3];
            v2f acc = (v2f){g0.x*u0, g0.y*u0};
            acc = __builtin_elementwise_fma((v2f){u1,u1}, (v2f){g1.x,g1.y}, acc);
            acc = __builtin_elementwise_fma((v2f){u2,u2}, (v2f){g2.x,g2.y}, acc);
            acc = __builtin_elementwise_fma((v2f){u3_,u3_}, (v2f){g3.x,g3.y}, acc);
            W[p][i] = acc;
        }
    }
    // Phase-A mapping: reg bits (pos0..3) = logical {5,6,7,8};
    // lane bits (0..5) = logical {0,1,2,3,4,9}.
    const int l0 = lane&1, l1=(lane>>1)&1, l2=(lane>>2)&1,
              l3=(lane>>3)&1, l4=(lane>>4)&1, l5=(lane>>5)&1;
    v2f W3k = vsel(l3, vsel(l2, W[3][3], W[3][2]), vsel(l2, W[3][1], W[3][0]));
    v2f W4k = vsel(l1, vsel(l0, W[4][3], W[4][2]), vsel(l0, W[4][1], W[4][0]));
    v2f UL  = cmulv(W3k, W4k);
    v2f W2lo = vsel(l4, W[2][1], W[2][0]);   // k2 = 2*r0 + l4, r0=0
    v2f W2hi = vsel(l4, W[2][3], W[2][2]);   // r0=1
    v2f P0 = cmulv(UL, vsel(l5, W[0][2], W[0][0]));  // k0 = 2*l5 + r3, r3=0
    v2f P1 = cmulv(UL, vsel(l5, W[0][3], W[0][1]));  // r3=1
    v2f PW[2][4];
    #pragma unroll
    for (int j = 0; j < 4; ++j) {
        PW[0][j] = cmulv(P0, W[1][j]);
        PW[1][j] = cmulv(P1, W[1][j]);
    }
    v2f st[16];
    #pragma unroll
    for (int r = 0; r < 16; ++r)
        st[r] = cmulv(PW[(r>>3)&1][(r>>1)&3], (r&1) ? W2hi : W2lo);

    const float2* gm = gates;

    // Phase A: reg {5,6,7,8}
    gate4<3,2>(st, gm + 5*16);    // g5  {8,7}
    gate4<1,0>(st, gm + 6*16);    // g6  {6,5}
    crot4<1,2>(st, gm + 10*16);   // g10 ctrl6,tgt7
    permute<0>(st, lds, lane);
    // Phase B: reg {1,2,3,4}
    gate4<3,2>(st, gm + 7*16);    // g7  {4,3}
    gate4<1,0>(st, gm + 8*16);    // g8  {2,1}
    crot4<1,2>(st, gm + 12*16);   // g12 ctrl2,tgt3
    permute<1>(st, lds, lane);
    // Phase C: reg {4,5,8,9}
    crot4<2,3>(st, gm + 9*16);    // g9  ctrl8,tgt9
    crot4<0,1>(st, gm + 11*16);   // g11 ctrl4,tgt5
    permute<2>(st, lds, lane);
    // Phase D: reg {0,1,3,5}
    crot4<0,1>(st, gm + 13*16);   // g13 ctrl0,tgt1
    gate4<3,2>(st, gm + 15*16);   // g15 {5,3}
    gate4<2,1>(st, gm + 17*16);   // g17 {3,1}
    permute<3>(st, lds, lane);
    // Phase E: reg {3,5,7,9}
    gate4<3,2>(st, gm + 14*16);   // g14 {9,7}
    gate4<2,1>(st, gm + 16*16);   // g16 {7,5}
    crot4<2,3>(st, gm + 18*16);   // g18 ctrl7,tgt9
    crot4<0,1>(st, gm + 19*16);   // g19 ctrl3,tgt5
    permute<4>(st, lds, lane);
    // Phase F: reg {0,1,5,9}
    gate4<3,2>(st, gm + 20*16);   // g20 {9,5}
    gate4<2,1>(st, gm + 21*16);   // g21 {5,1}
    crot4<2,3>(st, gm + 22*16);   // g22 ctrl5,tgt9

    // ---- <Z0>: logical bit 9 sits at reg-index bit 3 in phase F.
    float accp = 0.f, accm = 0.f;
    #pragma unroll
    for (int r = 0; r < 16; ++r) {
        v2f a = st[r];
        float p2 = fmaf(a.x, a.x, a.y*a.y);
        if ((r >> 3) & 1) accm += p2; else accp += p2;
    }
    float acc = accp - accm;
    #pragma unroll
    for (int off = 32; off >= 1; off >>= 1) acc += __shfl_xor(acc, off);
    if (lane == 0) out[s] = acc;
}

extern "C" void kernel_launch(void* const* d_in, const int* in_sizes, int n_in,
                              void* d_out, int out_size, void* d_ws, size_t ws_size,
                              hipStream_t stream) {
    const float* x     = (const float*)d_in[0];
    const float* fc_w  = (const float*)d_in[1];
    const float* fc_b  = (const float*)d_in[2];
    const float* convp = (const float*)d_in[3];
    const float* poolp = (const float*)d_in[4];
    float2* gates = (float2*)d_ws;   // 23*16*8 = 2944 bytes
    float* out = (float*)d_out;

    precompute_gates<<<1, 64, 0, stream>>>(convp, poolp, gates);
    hqtcn_sim<<<16*NWIN, 64, 0, stream>>>(x, fc_w, fc_b, gates, out);
}

// Round 5
// 27.915 us; speedup vs baseline: 2.2083x; 1.1275x over previous
//
#include <hip/hip_runtime.h>

#define NWIN 121
#define NQ 10
#define NGATES 23
#define WPB 4          // waves (samples) per block

typedef float v2f __attribute__((ext_vector_type(2)));

// Gate schedule (static: depth=3, wires [0..9] -> [0,2,4,6,8] -> [0,4,8]).
// type 0 = fused conv block (u3⊗u3 · XX·YY·ZZ · u3⊗u3), type 1 = CRot.
static constexpr int GT [NGATES] = {0,0,0,0,0,0,0,0,0, 1,1,1,1,1, 0,0,0,0, 1,1, 0,0, 1};
static constexpr int GL [NGATES] = {0,0,0,0,0,0,0,0,0, 0,0,0,0,0, 1,1,1,1, 1,1, 2,2, 2};
static constexpr int GP [NGATES] = {0,2,4,6,8,1,3,5,7, 0,1,2,3,4, 0,2,1,3, 0,1, 0,1, 0};
__device__ static const int dGT[NGATES] = {0,0,0,0,0,0,0,0,0, 1,1,1,1,1, 0,0,0,0, 1,1, 0,0, 1};
__device__ static const int dGL[NGATES] = {0,0,0,0,0,0,0,0,0, 0,0,0,0,0, 1,1,1,1, 1,1, 2,2, 2};
__device__ static const int dGP[NGATES] = {0,2,4,6,8,1,3,5,7, 0,1,2,3,4, 0,2,1,3, 0,1, 0,1, 0};

// ---- register-resident phase schedule (g0..g4 absorbed into init) ---------
// Logical amp bit = 9 - qubit. Phases A..F (0..5): 4 logical bits in the
// register index (REGB[ph][k] = logical bit at reg-index bit k), 6 in the
// lane index. 5 LDS permutes between phases, XOR-swizzled so the 4 slot
// low bits are rank-4 lane-driven on BOTH write and read sides.
__host__ __device__ constexpr int REGB[6][4] = {
    {5,6,7,8},{1,2,3,4},{4,5,8,9},{0,1,3,5},{3,5,7,9},{0,1,5,9}};
__host__ __device__ constexpr int LANEB[6][6] = {
    {0,1,2,3,4,9},{0,5,6,7,8,9},{0,1,2,3,6,7},
    {2,4,6,7,8,9},{0,1,2,4,6,8},{2,3,4,6,7,8}};

__host__ __device__ constexpr int hswz(int p, int L){
    return p==0 ? ((((L>>5)&1)<<1)|(((L>>6)&1)<<2)|(((L>>7)&1)<<3))
         : p==1 ? ((((L>>6)&1)<<1)|(((L>>7)&1)<<2)|(((L>>8)&1)<<3))
         : p==2 ? (((L>>4)&1)|(((L>>6)&1)<<1)|(((L>>7)&1)<<3))
         :        (((L>>4)&1)|(((L>>6)&1)<<1)|(((L>>8)&1)<<3));  // p=3,4
}
__host__ __device__ constexpr int offsL(int ph, int r){
    int o = 0;
    for (int k=0;k<4;++k) if ((r>>k)&1) o |= 1<<REGB[ph][k];
    return o;
}

struct cpx { float x, y; };
__device__ __forceinline__ cpx cmul(cpx a, cpx b){ return {a.x*b.x - a.y*b.y, a.x*b.y + a.y*b.x}; }
__device__ __forceinline__ cpx cadd(cpx a, cpx b){ return {a.x+b.x, a.y+b.y}; }
__device__ __forceinline__ cpx cscale(float s, cpx a){ return {s*a.x, s*a.y}; }
__device__ __forceinline__ cpx cexp_i(float t){ return {cosf(t), sinf(t)}; }
__device__ __forceinline__ cpx mulnegi(cpx z){ return {z.y, -z.x}; }   // -i*z

__device__ __forceinline__ void u3m(cpx A[2][2], float th, float ph, float de){
    float ct = cosf(0.5f*th), st = sinf(0.5f*th);
    cpx ed  = cexp_i(de);
    cpx ep  = cexp_i(ph);
    cpx epd = cexp_i(ph + de);
    A[0][0] = {ct, 0.f};
    A[0][1] = {-ed.x*st, -ed.y*st};
    A[1][0] = { ep.x*st,  ep.y*st};
    A[1][1] = { epd.x*ct, epd.y*ct};
}

// Build fused gate g's 4x4 complex matrix into M (registers).
__device__ __forceinline__ void build_gate(int g, const float* __restrict__ conv,
                                           const float* __restrict__ pool,
                                           cpx (&M)[4][4])
{
    int l = dGL[g], pi = dGP[g];
    if (dGT[g] == 0) {
        const float* W1 = conv + l*150 + pi*15;
        const float* W2 = conv + l*150 + (pi+1)*15;
        cpx A1[2][2], B1[2][2], A2[2][2], B2[2][2];
        u3m(A1, W1[0],  W1[1],  W1[2]);
        u3m(B1, W2[3],  W2[4],  W2[5]);
        u3m(A2, W1[9],  W1[10], W1[11]);
        u3m(B2, W2[12], W2[13], W2[14]);
        cpx T[4][4];
        #pragma unroll
        for (int r1=0;r1<2;++r1)
        #pragma unroll
        for (int r2=0;r2<2;++r2)
        #pragma unroll
        for (int c1=0;c1<2;++c1)
        #pragma unroll
        for (int c2=0;c2<2;++c2)
            T[2*r1+r2][2*c1+c2] = cmul(A1[r1][c1], B1[r2][c2]);
        float tz = W1[6];
        cpx em = cexp_i(-0.5f*tz), ep = cexp_i(0.5f*tz);
        cpx dz[4] = {em, ep, ep, em};
        #pragma unroll
        for (int r=0;r<4;++r)
        #pragma unroll
        for (int c=0;c<4;++c) T[r][c] = cmul(dz[r], T[r][c]);
        float ty = W1[7]; float cy = cosf(0.5f*ty), sy = sinf(0.5f*ty);
        cpx T2_[4][4];
        #pragma unroll
        for (int c=0;c<4;++c) {
            T2_[0][c] = cadd(cscale(cy,T[0][c]), mulnegi(cscale(-sy, T[3][c])));
            T2_[1][c] = cadd(cscale(cy,T[1][c]), mulnegi(cscale( sy, T[2][c])));
            T2_[2][c] = cadd(cscale(cy,T[2][c]), mulnegi(cscale( sy, T[1][c])));
            T2_[3][c] = cadd(cscale(cy,T[3][c]), mulnegi(cscale(-sy, T[0][c])));
        }
        float tx = W1[8]; float cx = cosf(0.5f*tx), sx = sinf(0.5f*tx);
        cpx T3_[4][4];
        #pragma unroll
        for (int c=0;c<4;++c) {
            T3_[0][c] = cadd(cscale(cx,T2_[0][c]), mulnegi(cscale(sx, T2_[3][c])));
            T3_[1][c] = cadd(cscale(cx,T2_[1][c]), mulnegi(cscale(sx, T2_[2][c])));
            T3_[2][c] = cadd(cscale(cx,T2_[2][c]), mulnegi(cscale(sx, T2_[1][c])));
            T3_[3][c] = cadd(cscale(cx,T2_[3][c]), mulnegi(cscale(sx, T2_[0][c])));
        }
        cpx K2[4][4];
        #pragma unroll
        for (int r1=0;r1<2;++r1)
        #pragma unroll
        for (int r2=0;r2<2;++r2)
        #pragma unroll
        for (int c1=0;c1<2;++c1)
        #pragma unroll
        for (int c2=0;c2<2;++c2)
            K2[2*r1+r2][2*c1+c2] = cmul(A2[r1][c1], B2[r2][c2]);
        #pragma unroll
        for (int r=0;r<4;++r)
        #pragma unroll
        for (int c=0;c<4;++c) {
            cpx acc = {0.f, 0.f};
            #pragma unroll
            for (int m=0;m<4;++m) acc = cadd(acc, cmul(K2[r][m], T3_[m][c]));
            M[r][c] = acc;
        }
    } else {
        const float* Pp = pool + l*15 + pi*3;
        float phi = Pp[0], th = Pp[1], om = Pp[2];
        float ct = cosf(0.5f*th), st = sinf(0.5f*th);
        #pragma unroll
        for (int r=0;r<4;++r)
        #pragma unroll
        for (int c=0;c<4;++c) M[r][c] = {0.f, 0.f};
        M[0][0] = {1.f, 0.f};
        M[1][1] = {1.f, 0.f};
        M[2][2] = cscale( ct, cexp_i(-0.5f*(phi+om)));
        M[2][3] = cscale(-st, cexp_i( 0.5f*(phi-om)));
        M[3][2] = cscale( st, cexp_i(-0.5f*(phi-om)));
        M[3][3] = cscale( ct, cexp_i( 0.5f*(phi+om)));
    }
}

// ---- sim helpers -----------------------------------------------------------

// complex fused-multiply-add: acc += m * v  (2x v_pk_fma_f32 expected)
__device__ __forceinline__ v2f cfma(v2f m, v2f v, v2f acc) {
    v2f sw = {v.y, v.x};
    v2f my = {-m.y, m.y};
    v2f t = __builtin_elementwise_fma(my, sw, acc);
    v2f mx = {m.x, m.x};
    return __builtin_elementwise_fma(mx, v, t);
}
__device__ __forceinline__ v2f cmulv(v2f a, v2f b) { return cfma(a, b, (v2f){0.f,0.f}); }
__device__ __forceinline__ v2f vsel(int c, v2f a, v2f b) {
    return (v2f){ c ? a.x : b.x, c ? a.y : b.y };
}

// wave-local LDS fence: drain this wave's outstanding DS ops; no s_barrier.
__device__ __forceinline__ void wave_lds_fence() {
    asm volatile("s_waitcnt lgkmcnt(0)" ::: "memory");
}

// dense 4x4 complex gate on register bits P1,P2; basis k = 2*bit_P1 + bit_P2
template<int P1, int P2>
__device__ __forceinline__ void gate4(v2f (&st)[16], const float2* __restrict__ g) {
    v2f m[16];
    #pragma unroll
    for (int k = 0; k < 16; ++k) { float2 t = g[k]; m[k] = (v2f){t.x, t.y}; }
    constexpr int M1 = 1 << P1, M2 = 1 << P2;
    #pragma unroll
    for (int b = 0; b < 16; ++b) {
        if (b & (M1 | M2)) continue;
        v2f v0 = st[b], v1 = st[b|M2], v2 = st[b|M1], v3 = st[b|M1|M2];
        #pragma unroll
        for (int row = 0; row < 4; ++row) {
            v2f acc = cfma(m[row*4+0], v0, (v2f){0.f, 0.f});
            acc = cfma(m[row*4+1], v1, acc);
            acc = cfma(m[row*4+2], v2, acc);
            acc = cfma(m[row*4+3], v3, acc);
            st[b | ((row>>1) ? M1 : 0) | ((row&1) ? M2 : 0)] = acc;
        }
    }
}

// CRot: identity on ctrl=0 half; active 2x2 block on ctrl(P1)=1 rows.
template<int P1, int P2>
__device__ __forceinline__ void crot4(v2f (&st)[16], const float2* __restrict__ g) {
    float2 t;
    t = g[10]; v2f m22 = {t.x, t.y};
    t = g[11]; v2f m23 = {t.x, t.y};
    t = g[14]; v2f m32 = {t.x, t.y};
    t = g[15]; v2f m33 = {t.x, t.y};
    constexpr int M1 = 1 << P1, M2 = 1 << P2;
    #pragma unroll
    for (int b = 0; b < 16; ++b) {
        if (!(b & M1) || (b & M2)) continue;   // ctrl=1, tgt=0 bases
        v2f v2_ = st[b], v3_ = st[b|M2];
        st[b]    = cfma(m23, v3_, cfma(m22, v2_, (v2f){0.f,0.f}));
        st[b|M2] = cfma(m33, v3_, cfma(m32, v2_, (v2f){0.f,0.f}));
    }
}

template<int PH>
__device__ __forceinline__ int base_of(int lane) {
    int b = 0;
    #pragma unroll
    for (int j = 0; j < 6; ++j) b |= ((lane >> j) & 1) << LANEB[PH][j];
    return b;
}

// LDS re-permute (wave-local buffer) from phase PERM's mapping to PERM+1's.
template<int PERM>
__device__ __forceinline__ void permute(v2f (&st)[16], char* lds, int lane) {
    int bw0 = base_of<PERM>(lane);
    int bw = (bw0 ^ hswz(PERM, bw0)) << 3;
    #pragma unroll
    for (int r = 0; r < 16; ++r) {
        const int o = offsL(PERM, r);
        const int C = (o ^ hswz(PERM, o)) << 3;
        *reinterpret_cast<v2f*>(lds + (bw ^ C)) = st[r];
    }
    wave_lds_fence();                 // writes visible to this wave's reads
    int br0 = base_of<PERM+1>(lane);
    int br = (br0 ^ hswz(PERM, br0)) << 3;
    #pragma unroll
    for (int r = 0; r < 16; ++r) {
        const int o = offsL(PERM+1, r);
        const int C = (o ^ hswz(PERM, o)) << 3;
        st[r] = *reinterpret_cast<const v2f*>(lds + (br ^ C));
    }
    wave_lds_fence();                 // reads done before next permute writes
}

// Single fused kernel. Block = 256 threads = 4 waves = 4 samples.
// Wave 0 (lanes 0..22) rebuilds the 23 fused gate matrices into LDS (once
// per block); each wave then simulates its own sample with register-resident
// state and a private 8KB LDS permute buffer (wave-local fences only).
__global__ __launch_bounds__(256) void hqtcn_fused(
    const float* __restrict__ x,      // (16, 32, 128)
    const float* __restrict__ fc_w,   // (10, 256)
    const float* __restrict__ fc_b,   // (10,)
    const float* __restrict__ conv,   // (3, 10, 15)
    const float* __restrict__ pool,   // (3, 5, 3)
    float* __restrict__ out)          // (1936,)
{
    __shared__ float2 gmat[NGATES*16];        // 2944 B gate matrices
    __shared__ float2 pbuf[WPB][1024];        // 8 KB per-wave permute buffers

    const int tid  = threadIdx.x;
    const int wid  = tid >> 6;
    const int lane = tid & 63;
    const int s = blockIdx.x * WPB + wid;     // sample id, 484*4 = 1936 exact
    const int b = s / NWIN, w = s % NWIN;
    char* lds = reinterpret_cast<char*>(&pbuf[wid][0]);

    // ---- angles (per wave)
    float xv[4];
    #pragma unroll
    for (int j = 0; j < 4; ++j) {
        int f = lane + 64*j;
        xv[j] = x[b*4096 + (f >> 3)*128 + w + (f & 7)];
    }
    float cq[NQ], sq[NQ];
    #pragma unroll
    for (int e = 0; e < NQ; ++e) {
        float v = 0.f;
        #pragma unroll
        for (int j = 0; j < 4; ++j)
            v = fmaf(xv[j], fc_w[e*256 + lane + 64*j], v);
        #pragma unroll
        for (int off = 32; off >= 1; off >>= 1) v += __shfl_xor(v, off);
        float h = 0.5f * (v + fc_b[e]);
        __sincosf(h, &sq[e], &cq[e]);
    }

    // ---- wave 0: build gate matrices into LDS
    if (tid < NGATES) {
        cpx M[4][4];
        build_gate(tid, conv, pool, M);
        #pragma unroll
        for (int r = 0; r < 4; ++r)
        #pragma unroll
        for (int c = 0; c < 4; ++c)
            gmat[tid*16 + r*4 + c] = make_float2(M[r][c].x, M[r][c].y);
    }
    __syncthreads();    // the only block-wide barrier

    // ---- init: apply g0..g4 analytically. W[p] = G_p @ [cc',cs',sc',ss']
    // for qubit pair (2p, 2p+1); state = outer product of the five W vectors.
    v2f W[5][4];
    #pragma unroll
    for (int p = 0; p < 5; ++p) {
        float ca = cq[2*p], sa = sq[2*p], cb = cq[2*p+1], sb = sq[2*p+1];
        float u0 = ca*cb, u1 = ca*sb, u2 = sa*cb, u3_ = sa*sb;
        const float2* G = gmat + p*16;
        #pragma unroll
        for (int i = 0; i < 4; ++i) {
            float2 g0 = G[i*4+0], g1 = G[i*4+1], g2 = G[i*4+2], g3 = G[i*4+3];
            v2f acc = (v2f){g0.x*u0, g0.y*u0};
            acc = __builtin_elementwise_fma((v2f){u1,u1}, (v2f){g1.x,g1.y}, acc);
            acc = __builtin_elementwise_fma((v2f){u2,u2}, (v2f){g2.x,g2.y}, acc);
            acc = __builtin_elementwise_fma((v2f){u3_,u3_}, (v2f){g3.x,g3.y}, acc);
            W[p][i] = acc;
        }
    }
    // Phase-A mapping: reg bits (pos0..3) = logical {5,6,7,8};
    // lane bits (0..5) = logical {0,1,2,3,4,9}.
    const int l0 = lane&1, l1=(lane>>1)&1, l2=(lane>>2)&1,
              l3=(lane>>3)&1, l4=(lane>>4)&1, l5=(lane>>5)&1;
    v2f W3k = vsel(l3, vsel(l2, W[3][3], W[3][2]), vsel(l2, W[3][1], W[3][0]));
    v2f W4k = vsel(l1, vsel(l0, W[4][3], W[4][2]), vsel(l0, W[4][1], W[4][0]));
    v2f UL  = cmulv(W3k, W4k);
    v2f W2lo = vsel(l4, W[2][1], W[2][0]);   // k2 = 2*r0 + l4, r0=0
    v2f W2hi = vsel(l4, W[2][3], W[2][2]);   // r0=1
    v2f P0 = cmulv(UL, vsel(l5, W[0][2], W[0][0]));  // k0 = 2*l5 + r3, r3=0
    v2f P1 = cmulv(UL, vsel(l5, W[0][3], W[0][1]));  // r3=1
    v2f PW[2][4];
    #pragma unroll
    for (int j = 0; j < 4; ++j) {
        PW[0][j] = cmulv(P0, W[1][j]);
        PW[1][j] = cmulv(P1, W[1][j]);
    }
    v2f st[16];
    #pragma unroll
    for (int r = 0; r < 16; ++r)
        st[r] = cmulv(PW[(r>>3)&1][(r>>1)&3], (r&1) ? W2hi : W2lo);

    const float2* gm = gmat;

    // Phase A: reg {5,6,7,8}
    gate4<3,2>(st, gm + 5*16);    // g5  {8,7}
    gate4<1,0>(st, gm + 6*16);    // g6  {6,5}
    crot4<1,2>(st, gm + 10*16);   // g10 ctrl6,tgt7
    permute<0>(st, lds, lane);
    // Phase B: reg {1,2,3,4}
    gate4<3,2>(st, gm + 7*16);    // g7  {4,3}
    gate4<1,0>(st, gm + 8*16);    // g8  {2,1}
    crot4<1,2>(st, gm + 12*16);   // g12 ctrl2,tgt3
    permute<1>(st, lds, lane);
    // Phase C: reg {4,5,8,9}
    crot4<2,3>(st, gm + 9*16);    // g9  ctrl8,tgt9
    crot4<0,1>(st, gm + 11*16);   // g11 ctrl4,tgt5
    permute<2>(st, lds, lane);
    // Phase D: reg {0,1,3,5}
    crot4<0,1>(st, gm + 13*16);   // g13 ctrl0,tgt1
    gate4<3,2>(st, gm + 15*16);   // g15 {5,3}
    gate4<2,1>(st, gm + 17*16);   // g17 {3,1}
    permute<3>(st, lds, lane);
    // Phase E: reg {3,5,7,9}
    gate4<3,2>(st, gm + 14*16);   // g14 {9,7}
    gate4<2,1>(st, gm + 16*16);   // g16 {7,5}
    crot4<2,3>(st, gm + 18*16);   // g18 ctrl7,tgt9
    crot4<0,1>(st, gm + 19*16);   // g19 ctrl3,tgt5
    permute<4>(st, lds, lane);
    // Phase F: reg {0,1,5,9}
    gate4<3,2>(st, gm + 20*16);   // g20 {9,5}
    gate4<2,1>(st, gm + 21*16);   // g21 {5,1}
    crot4<2,3>(st, gm + 22*16);   // g22 ctrl5,tgt9

    // ---- <Z0>: logical bit 9 sits at reg-index bit 3 in phase F.
    float accp = 0.f, accm = 0.f;
    #pragma unroll
    for (int r = 0; r < 16; ++r) {
        v2f a = st[r];
        float p2 = fmaf(a.x, a.x, a.y*a.y);
        if ((r >> 3) & 1) accm += p2; else accp += p2;
    }
    float acc = accp - accm;
    #pragma unroll
    for (int off = 32; off >= 1; off >>= 1) acc += __shfl_xor(acc, off);
    if (lane == 0) out[s] = acc;
}

extern "C" void kernel_launch(void* const* d_in, const int* in_sizes, int n_in,
                              void* d_out, int out_size, void* d_ws, size_t ws_size,
                              hipStream_t stream) {
    const float* x     = (const float*)d_in[0];
    const float* fc_w  = (const float*)d_in[1];
    const float* fc_b  = (const float*)d_in[2];
    const float* convp = (const float*)d_in[3];
    const float* poolp = (const float*)d_in[4];
    float* out = (float*)d_out;

    hqtcn_fused<<<(16*NWIN)/WPB, 64*WPB, 0, stream>>>(x, fc_w, fc_b, convp, poolp, out);
}